// Round 1
// baseline (2981.053 us; speedup 1.0000x reference)
//
#include <hip/hip_runtime.h>
#include <hip/hip_bf16.h>
#include <math.h>

// Problem constants
#define BB 256
#define T2C 1026
#define TP1 1025
#define SS 1024
#define HH 32
#define EVN 32
#define VOCAB 35
#define NH7 224            // 7*H
#define NROWS 262400       // B*Tp1
#define NROWS_USED 262144  // B*S
#define EPSF 2.220446049250313e-16f

// ws layout in floats:
//  [0, NROWS*128)          ccdo rows: per (b,t): c[32], cbar[32], delta[32], o[32]
//  [H_F, +NROWS*32)        h rows
//  [EMBW_F, +35*224)       EmbW (x@W[:32,:] + b per vocab word)
//  [ACC_F, +1024)          accum: numer[256] | den[256] | loglam_b[256] | nev_b[256]
#define H_F    ((size_t)NROWS * 128)               // 33,587,200
#define EMBW_F (H_F + (size_t)NROWS * HH)          // 41,984,000
#define ACC_F  (EMBW_F + (size_t)VOCAB * NH7)      // 41,991,840

__device__ __forceinline__ float softplusf(float x) {
    return fmaxf(x, 0.f) + log1pf(expf(-fabsf(x)));
}

// ---------------- K0: EmbW precompute + zero accumulators ----------------
__global__ __launch_bounds__(256) void k0_embw(const float* __restrict__ Emb,
                                               const float* __restrict__ W,
                                               const float* __restrict__ bias,
                                               float* __restrict__ ws) {
    int j = threadIdx.x;
    for (int idx = j; idx < 1024; idx += 256) ws[ACC_F + idx] = 0.f;
    __shared__ float embs[VOCAB * HH];
    for (int idx = j; idx < VOCAB * HH; idx += 256) embs[idx] = Emb[idx];
    __syncthreads();
    if (j < NH7) {
        for (int v = 0; v < VOCAB; v++) {
            float s = bias[j];
#pragma unroll
            for (int k = 0; k < HH; k++) s = fmaf(embs[v * HH + k], W[k * NH7 + j], s);
            ws[EMBW_F + v * NH7 + j] = s;
        }
    }
}

// ---------------- K1: the sequential CTLSTM scan (1 block per batch) ----------------
__global__ __launch_bounds__(256) void k1_recur(const int* __restrict__ event,
                                                const float* __restrict__ dtime,
                                                const float* __restrict__ W,
                                                float* ws) {
    const int b = blockIdx.x;
    const int j = threadIdx.x;
    __shared__ float embw[VOCAB * NH7];
    __shared__ float dt_s[TP1];
    __shared__ int ev_s[TP1];
    __shared__ __align__(16) float h_s[HH];
    __shared__ float g_s[NH7];

    for (int idx = j; idx < VOCAB * NH7; idx += 256) embw[idx] = ws[EMBW_F + idx];
    for (int idx = j; idx < TP1; idx += 256) {
        ev_s[idx] = event[b * T2C + idx];
        dt_s[idx] = dtime[b * T2C + idx + 1];
    }
    if (j < HH) h_s[j] = 0.f;

    float wk[HH];
    if (j < NH7) {
#pragma unroll
        for (int k = 0; k < HH; k++) wk[k] = W[(HH + k) * NH7 + j];
    }
    float c_m = 0.f, cb_m = 0.f;
    float* ccdo_base = ws + (size_t)b * TP1 * 128;
    float* h_base = ws + H_F + (size_t)b * TP1 * HH;
    __syncthreads();

    for (int t = 0; t < TP1; t++) {
        if (j < NH7) {
            int evt = ev_s[t];
            float acc = embw[evt * NH7 + j];
            const float4* h4 = (const float4*)h_s;
#pragma unroll
            for (int q = 0; q < 8; q++) {
                float4 hv = h4[q];
                acc = fmaf(hv.x, wk[4 * q + 0], acc);
                acc = fmaf(hv.y, wk[4 * q + 1], acc);
                acc = fmaf(hv.z, wk[4 * q + 2], acc);
                acc = fmaf(hv.w, wk[4 * q + 3], acc);
            }
            int g = j >> 5;
            float val;
            if (g == 2) val = tanhf(acc);                       // z
            else if (g == 6) val = softplusf(acc);              // delta
            else val = 1.f / (1.f + expf(-acc));                // i,f,o,ib,fb
            g_s[j] = val;
        }
        __syncthreads();
        if (j < HH) {
            float i_ = g_s[j], f_ = g_s[HH + j], z_ = g_s[2 * HH + j], o_ = g_s[3 * HH + j];
            float ib_ = g_s[4 * HH + j], fb_ = g_s[5 * HH + j], dl = g_s[6 * HH + j];
            float c  = fmaf(f_, c_m, i_ * z_);
            float cb = fmaf(fb_, cb_m, ib_ * z_);
            float e  = expf(-dl * dt_s[t]);
            float cn = cb + (c - cb) * e;
            float h  = o_ * tanhf(cn);
            c_m = cn; cb_m = cb;
            h_s[j] = h;
            float* row = ccdo_base + t * 128;
            row[j] = c; row[HH + j] = cb; row[2 * HH + j] = dl; row[3 * HH + j] = o_;
            h_base[t * HH + j] = h;
        }
        __syncthreads();
    }
}

// ---------------- K2: lambda_sample + per-batch integral accumulators ----------------
__global__ __launch_bounds__(256) void k2_sample(const float* __restrict__ dts,
                                                 const float* __restrict__ msk,
                                                 const float* __restrict__ Wl,
                                                 float* ws,
                                                 float* __restrict__ out) {
    __shared__ float wlT[HH * EVN];  // [k][e]
    __shared__ float sh_s[8][HH];
    int tid = threadIdx.x;
    for (int idx = tid; idx < EVN * HH; idx += 256) {
        int e = idx >> 5, k = idx & 31;
        wlT[k * EVN + e] = Wl[idx];
    }
    int rowg = tid >> 5, lane = tid & 31;
    int rr = blockIdx.x * 8 + rowg;  // rr = b*1025+t = b'*1024+s  (identity mapping)
    const float* row = ws + (size_t)rr * 128;
    float c = row[lane], cb = row[HH + lane], dl = row[2 * HH + lane], o = row[3 * HH + lane];
    float e_ = expf(-dl * dts[rr]);
    float cd = cb + (c - cb) * e_;
    sh_s[rowg][lane] = o * tanhf(cd);
    __syncthreads();
    float acc = 0.f;
#pragma unroll
    for (int k = 0; k < HH; k++) acc = fmaf(sh_s[rowg][k], wlT[k * EVN + lane], acc);
    float sp = softplusf(acc);
    out[2 + (size_t)rr * EVN + lane] = sp;
    float lsum = sp;
    for (int m = 16; m >= 1; m >>= 1) lsum += __shfl_xor(lsum, m, 32);
    if (lane == 0) {
        float m_ = msk[rr];
        int bp = rr >> 10;
        atomicAdd(ws + ACC_F + bp, lsum * m_);
        atomicAdd(ws + ACC_F + 256 + bp, m_);
    }
}

// ---------------- K3: log-lambda at target + event count ----------------
__global__ __launch_bounds__(256) void k3_loglam(const int* __restrict__ event,
                                                 const float* __restrict__ Wl,
                                                 float* ws) {
    int tid = threadIdx.x;
    int rowg = tid >> 5, lane = tid & 31;
    int row = blockIdx.x * 8 + rowg;  // 0..262399 ; row = b*1025+t
    int b = row / TP1;
    int t = row - b * TP1;
    int tgt = event[b * T2C + t + 1];
    if (tgt < EVN) {
        const float* hrow = ws + H_F + (size_t)row * HH;
        float p = hrow[lane] * Wl[tgt * HH + lane];
        for (int m = 16; m >= 1; m >>= 1) p += __shfl_xor(p, m, 32);
        if (lane == 0) {
            float ll = logf(softplusf(p) + EPSF);
            atomicAdd(ws + ACC_F + 512 + b, ll);
            atomicAdd(ws + ACC_F + 768 + b, 1.f);
        }
    }
}

// ---------------- K4: final reduction ----------------
__global__ __launch_bounds__(256) void k4_final(const float* __restrict__ duration,
                                                float* ws,
                                                float* __restrict__ out) {
    __shared__ float r1[256], r2[256];
    int tid = threadIdx.x;
    float nmr = ws[ACC_F + tid];
    float den = ws[ACC_F + 256 + tid];
    float llb = ws[ACC_F + 512 + tid];
    float nev = ws[ACC_F + 768 + tid];
    float obj = (nmr / den) * duration[tid] - llb;  // integral_b - sum_t loglam
    r1[tid] = obj;
    r2[tid] = nev;
    __syncthreads();
    for (int ofs = 128; ofs > 0; ofs >>= 1) {
        if (tid < ofs) { r1[tid] += r1[tid + ofs]; r2[tid] += r2[tid + ofs]; }
        __syncthreads();
    }
    if (tid == 0) { out[0] = r1[0]; out[1] = r2[0]; }
}

extern "C" void kernel_launch(void* const* d_in, const int* in_sizes, int n_in,
                              void* d_out, int out_size, void* d_ws, size_t ws_size,
                              hipStream_t stream) {
    const int*   event    = (const int*)d_in[0];
    const float* dtime    = (const float*)d_in[1];
    const float* duration = (const float*)d_in[2];
    const float* dts      = (const float*)d_in[3];
    // d_in[4] index_of_hidden_sampling: dead in reference
    const float* msk      = (const float*)d_in[5];
    const float* Emb      = (const float*)d_in[6];
    const float* W        = (const float*)d_in[7];
    const float* bias     = (const float*)d_in[8];
    const float* Wl       = (const float*)d_in[9];
    float* out = (float*)d_out;
    float* ws  = (float*)d_ws;

    k0_embw<<<1, 256, 0, stream>>>(Emb, W, bias, ws);
    k1_recur<<<BB, 256, 0, stream>>>(event, dtime, W, ws);
    k2_sample<<<NROWS_USED / 8, 256, 0, stream>>>(dts, msk, Wl, ws, out);
    k3_loglam<<<NROWS / 8, 256, 0, stream>>>(event, Wl, ws);
    k4_final<<<1, 256, 0, stream>>>(duration, ws, out);
}

// Round 2
// 1105.329 us; speedup vs baseline: 2.6970x; 2.6970x over previous
//
#include <hip/hip_runtime.h>
#include <hip/hip_bf16.h>
#include <math.h>

// Problem constants
#define BB 256
#define T2C 1026
#define TP1 1025
#define SS 1024
#define HH 32
#define EVN 32
#define VOCAB 35
#define NH7 224            // 7*H
#define NROWS 262400       // B*Tp1
#define NROWS_USED 262144  // B*S
#define EPSF 2.220446049250313e-16f

// ws layout in floats:
//  [0, NROWS*128)          ccdo rows: per (b,t): c[32], cbar[32], delta[32], o[32]
//  [H_F, +NROWS*32)        h rows
//  [EMBW_F, +35*224)       EmbW (x@W[:32,:] + b per vocab word)
//  [ACC_F, +1024)          per-b scalars: numer[256] | den[256] | loglam_b[256] | nev_b[256]
#define H_F    ((size_t)NROWS * 128)               // 33,587,200
#define EMBW_F (H_F + (size_t)NROWS * HH)          // 41,984,000
#define ACC_F  (EMBW_F + (size_t)VOCAB * NH7)      // 41,991,840

__device__ __forceinline__ float softplusf(float x) {
    return fmaxf(x, 0.f) + log1pf(expf(-fabsf(x)));
}

// ---------------- K0: EmbW precompute ----------------
__global__ __launch_bounds__(256) void k0_embw(const float* __restrict__ Emb,
                                               const float* __restrict__ W,
                                               const float* __restrict__ bias,
                                               float* __restrict__ ws) {
    int j = threadIdx.x;
    __shared__ float embs[VOCAB * HH];
    for (int idx = j; idx < VOCAB * HH; idx += 256) embs[idx] = Emb[idx];
    __syncthreads();
    if (j < NH7) {
        for (int v = 0; v < VOCAB; v++) {
            float s = bias[j];
#pragma unroll
            for (int k = 0; k < HH; k++) s = fmaf(embs[v * HH + k], W[k * NH7 + j], s);
            ws[EMBW_F + v * NH7 + j] = s;
        }
    }
}

// ---------------- K1: the sequential CTLSTM scan (1 block per batch) ----------------
__global__ __launch_bounds__(256) void k1_recur(const int* __restrict__ event,
                                                const float* __restrict__ dtime,
                                                const float* __restrict__ W,
                                                float* ws) {
    const int b = blockIdx.x;
    const int j = threadIdx.x;
    __shared__ float embw[VOCAB * NH7];
    __shared__ float dt_s[TP1];
    __shared__ int ev_s[TP1];
    __shared__ __align__(16) float h_s[HH];
    __shared__ float g_s[NH7];

    for (int idx = j; idx < VOCAB * NH7; idx += 256) embw[idx] = ws[EMBW_F + idx];
    for (int idx = j; idx < TP1; idx += 256) {
        ev_s[idx] = event[b * T2C + idx];
        dt_s[idx] = dtime[b * T2C + idx + 1];
    }
    if (j < HH) h_s[j] = 0.f;

    float wk[HH];
    if (j < NH7) {
#pragma unroll
        for (int k = 0; k < HH; k++) wk[k] = W[(HH + k) * NH7 + j];
    }
    float c_m = 0.f, cb_m = 0.f;
    float* ccdo_base = ws + (size_t)b * TP1 * 128;
    float* h_base = ws + H_F + (size_t)b * TP1 * HH;
    __syncthreads();

    for (int t = 0; t < TP1; t++) {
        if (j < NH7) {
            int evt = ev_s[t];
            float acc = embw[evt * NH7 + j];
            const float4* h4 = (const float4*)h_s;
#pragma unroll
            for (int q = 0; q < 8; q++) {
                float4 hv = h4[q];
                acc = fmaf(hv.x, wk[4 * q + 0], acc);
                acc = fmaf(hv.y, wk[4 * q + 1], acc);
                acc = fmaf(hv.z, wk[4 * q + 2], acc);
                acc = fmaf(hv.w, wk[4 * q + 3], acc);
            }
            int g = j >> 5;
            float val;
            if (g == 2) val = tanhf(acc);                       // z
            else if (g == 6) val = softplusf(acc);              // delta
            else val = 1.f / (1.f + expf(-acc));                // i,f,o,ib,fb
            g_s[j] = val;
        }
        __syncthreads();
        if (j < HH) {
            float i_ = g_s[j], f_ = g_s[HH + j], z_ = g_s[2 * HH + j], o_ = g_s[3 * HH + j];
            float ib_ = g_s[4 * HH + j], fb_ = g_s[5 * HH + j], dl = g_s[6 * HH + j];
            float c  = fmaf(f_, c_m, i_ * z_);
            float cb = fmaf(fb_, cb_m, ib_ * z_);
            float e  = expf(-dl * dt_s[t]);
            float cn = cb + (c - cb) * e;
            float h  = o_ * tanhf(cn);
            c_m = cn; cb_m = cb;
            h_s[j] = h;
            float* row = ccdo_base + t * 128;
            row[j] = c; row[HH + j] = cb; row[2 * HH + j] = dl; row[3 * HH + j] = o_;
            h_base[t * HH + j] = h;
        }
        __syncthreads();
    }
}

// ---------------- K2: lambda_sample + per-batch integral (1 block per b, no atomics) ----------------
__global__ __launch_bounds__(256) void k2_sample(const float* __restrict__ dts,
                                                 const float* __restrict__ msk,
                                                 const float* __restrict__ Wl,
                                                 float* ws,
                                                 float* __restrict__ out) {
    __shared__ float wlT[HH * EVN];  // wlT[k][e] = Wl[e][k]
    __shared__ float sh_s[8][HH];
    __shared__ float redn[8], redd[8];
    const int tid = threadIdx.x;
    const int b = blockIdx.x;
    for (int idx = tid; idx < EVN * HH; idx += 256) {
        int k = idx >> 5, e = idx & 31;
        wlT[idx] = Wl[e * HH + k];
    }
    const int rowg = tid >> 5, lane = tid & 31;
    float accn = 0.f, accd = 0.f;
    __syncthreads();

    for (int it = 0; it < SS / 8; it++) {
        const size_t rr = (size_t)b * SS + it * 8 + rowg;
        const float* row = ws + rr * 128;
        float c = row[lane], cb = row[HH + lane], dl = row[2 * HH + lane], o = row[3 * HH + lane];
        float e_ = expf(-dl * dts[rr]);
        float cd = cb + (c - cb) * e_;
        // sh_s[rowg][*] is written and read only by this 32-lane group (same wave):
        // no __syncthreads needed; compiler orders via lgkmcnt.
        sh_s[rowg][lane] = o * tanhf(cd);
        float acc = 0.f;
#pragma unroll
        for (int k = 0; k < HH; k++) acc = fmaf(sh_s[rowg][k], wlT[k * EVN + lane], acc);
        float sp = softplusf(acc);
        out[2 + rr * EVN + lane] = sp;
        float ls = sp;
#pragma unroll
        for (int m = 16; m >= 1; m >>= 1) ls += __shfl_xor(ls, m, 32);
        float m_ = msk[rr];
        accn = fmaf(ls, m_, accn);   // same value on all 32 lanes
        accd += m_;
    }
    if (lane == 0) { redn[rowg] = accn; redd[rowg] = accd; }
    __syncthreads();
    if (tid == 0) {
        float n = 0.f, d = 0.f;
#pragma unroll
        for (int g = 0; g < 8; g++) { n += redn[g]; d += redd[g]; }
        ws[ACC_F + b] = n;
        ws[ACC_F + 256 + b] = d;
    }
}

// ---------------- K3: log-lambda at target + event count (1 block per b, no atomics) ----------------
__global__ __launch_bounds__(256) void k3_loglam(const int* __restrict__ event,
                                                 const float* __restrict__ Wl,
                                                 float* ws) {
    __shared__ float wl_s[EVN * HH];
    __shared__ float redl[8], redc[8];
    const int tid = threadIdx.x;
    const int b = blockIdx.x;
    for (int idx = tid; idx < EVN * HH; idx += 256) wl_s[idx] = Wl[idx];
    const int rowg = tid >> 5, lane = tid & 31;
    float accl = 0.f, accc = 0.f;
    __syncthreads();

    for (int t = rowg; t < TP1; t += 8) {
        int tgt = event[b * T2C + t + 1];
        if (tgt < EVN) {
            const float* hrow = ws + H_F + ((size_t)b * TP1 + t) * HH;
            float p = hrow[lane] * wl_s[tgt * HH + lane];
#pragma unroll
            for (int m = 16; m >= 1; m >>= 1) p += __shfl_xor(p, m, 32);
            accl += logf(softplusf(p) + EPSF);  // same on all lanes
            accc += 1.f;
        }
    }
    if (lane == 0) { redl[rowg] = accl; redc[rowg] = accc; }
    __syncthreads();
    if (tid == 0) {
        float l = 0.f, c = 0.f;
#pragma unroll
        for (int g = 0; g < 8; g++) { l += redl[g]; c += redc[g]; }
        ws[ACC_F + 512 + b] = l;
        ws[ACC_F + 768 + b] = c;
    }
}

// ---------------- K4: final reduction ----------------
__global__ __launch_bounds__(256) void k4_final(const float* __restrict__ duration,
                                                float* ws,
                                                float* __restrict__ out) {
    __shared__ float r1[256], r2[256];
    int tid = threadIdx.x;
    float nmr = ws[ACC_F + tid];
    float den = ws[ACC_F + 256 + tid];
    float llb = ws[ACC_F + 512 + tid];
    float nev = ws[ACC_F + 768 + tid];
    float obj = (nmr / den) * duration[tid] - llb;  // integral_b - sum_t loglam
    r1[tid] = obj;
    r2[tid] = nev;
    __syncthreads();
    for (int ofs = 128; ofs > 0; ofs >>= 1) {
        if (tid < ofs) { r1[tid] += r1[tid + ofs]; r2[tid] += r2[tid + ofs]; }
        __syncthreads();
    }
    if (tid == 0) { out[0] = r1[0]; out[1] = r2[0]; }
}

extern "C" void kernel_launch(void* const* d_in, const int* in_sizes, int n_in,
                              void* d_out, int out_size, void* d_ws, size_t ws_size,
                              hipStream_t stream) {
    const int*   event    = (const int*)d_in[0];
    const float* dtime    = (const float*)d_in[1];
    const float* duration = (const float*)d_in[2];
    const float* dts      = (const float*)d_in[3];
    // d_in[4] index_of_hidden_sampling: dead in reference
    const float* msk      = (const float*)d_in[5];
    const float* Emb      = (const float*)d_in[6];
    const float* W        = (const float*)d_in[7];
    const float* bias     = (const float*)d_in[8];
    const float* Wl       = (const float*)d_in[9];
    float* out = (float*)d_out;
    float* ws  = (float*)d_ws;

    k0_embw<<<1, 256, 0, stream>>>(Emb, W, bias, ws);
    k1_recur<<<BB, 256, 0, stream>>>(event, dtime, W, ws);
    k2_sample<<<BB, 256, 0, stream>>>(dts, msk, Wl, ws, out);
    k3_loglam<<<BB, 256, 0, stream>>>(event, Wl, ws);
    k4_final<<<1, 256, 0, stream>>>(duration, ws, out);
}